// Round 8
// baseline (440.080 us; speedup 1.0000x reference)
//
#include <hip/hip_runtime.h>
#include <hip/hip_bf16.h>
#include <hip/hip_cooperative_groups.h>
#include <math.h>

namespace cg = cooperative_groups;

typedef __bf16 bf16_t;
typedef bf16_t bf16x8 __attribute__((ext_vector_type(8)));
typedef bf16_t bf16x4 __attribute__((ext_vector_type(4)));
typedef float f32x4 __attribute__((ext_vector_type(4)));

#define L_TEXT 2048
#define N_TOKEN 2048
#define C_TEXT 3584
#define C_OUT 384
#define C_HID 768
#define BATCH 8
#define MAXROWS (BATCH * N_TOKEN)
#define PM 3072
#define NPAIR (BATCH * 6)
#define KSPLIT 4
#define KCHUNK (C_TEXT / KSPLIT)    // 896
#define KSPLIT2 4
#define KCHUNK2 (C_HID / KSPLIT2)   // 192
#define KSPLIT2F 2
#define KCHUNK2F (C_HID / KSPLIT2F) // 384 (fallback gemm2)

#define NW1 (C_HID * C_TEXT / 8)
#define NW2 (C_OUT * C_HID / 8)
#define NINV (MAXROWS / 4)
#define CVT_BLOCKS ((NW1 + NW2 + NINV) / 256)   // 1504 exactly
#define GCH (C_TEXT / 8)

// ============================================================================
//                          COOPERATIVE MEGA-KERNEL
// ============================================================================
__global__ __launch_bounds__(256, 2) void mega_kernel(
    const float* __restrict__ X, const int* __restrict__ tm,
    const int* __restrict__ ctid, const int* __restrict__ cdrid,
    const int* __restrict__ bct, const int* __restrict__ brt,
    const float* __restrict__ W1, const float* __restrict__ b1,
    const float* __restrict__ W2, const float* __restrict__ b2,
    const float* __restrict__ scale,
    bf16_t* __restrict__ W1b, bf16_t* __restrict__ W2b,
    int* __restrict__ inv, int* __restrict__ count, int* __restrict__ vcnt,
    int* __restrict__ rows_src, int* __restrict__ trowL, int* __restrict__ pidxL,
    bf16_t* __restrict__ H, float* __restrict__ P, float* __restrict__ outp)
{
    cg::grid_group grid = cg::this_grid();
    const int nb = gridDim.x;
    const int t = threadIdx.x;

    __shared__ __align__(16) bf16_t As[2][128][40];   // 20 KB
    __shared__ __align__(16) bf16_t Bs[2][128][40];   // 20 KB
    bf16_t* AsF = &As[0][0][0];
    bf16_t* BsF = &Bs[0][0][0];

    // ================= P0: W cvt + inv=-1 + per-pair mask scans =================
    for (int u = blockIdx.x; u < CVT_BLOCKS + NPAIR; u += nb) {
        if (u < CVT_BLOCKS) {
            int idx = u * 256 + t;
            if (idx < NW1) {
                int i = idx * 8;
                float4 v0 = *(const float4*)(W1 + i);
                float4 v1 = *(const float4*)(W1 + i + 4);
                bf16x8 o;
                o[0] = (bf16_t)v0.x; o[1] = (bf16_t)v0.y; o[2] = (bf16_t)v0.z; o[3] = (bf16_t)v0.w;
                o[4] = (bf16_t)v1.x; o[5] = (bf16_t)v1.y; o[6] = (bf16_t)v1.z; o[7] = (bf16_t)v1.w;
                *(bf16x8*)(W1b + i) = o;
            } else if (idx < NW1 + NW2) {
                int i = (idx - NW1) * 8;
                float4 v0 = *(const float4*)(W2 + i);
                float4 v1 = *(const float4*)(W2 + i + 4);
                bf16x8 o;
                o[0] = (bf16_t)v0.x; o[1] = (bf16_t)v0.y; o[2] = (bf16_t)v0.z; o[3] = (bf16_t)v0.w;
                o[4] = (bf16_t)v1.x; o[5] = (bf16_t)v1.y; o[6] = (bf16_t)v1.z; o[7] = (bf16_t)v1.w;
                *(bf16x8*)(W2b + i) = o;
            } else {
                int i = idx - NW1 - NW2;
                int4 m1 = {-1, -1, -1, -1};
                ((int4*)inv)[i] = m1;
            }
        } else if (t < 64) {
            const int bp = u - CVT_BLOCKS;
            const int lane = t;
            const int b = bp / 6, p = bp % 6;
            const int ct = (p < 3) ? 1 : 2;
            const int rt = 2 + 2 * (p % 3);
            const unsigned long long ltm = (1ull << lane) - 1ull;

            unsigned int tbits = 0, pbits = 0;
#pragma unroll
            for (int i = 0; i < 32; i++) {
                int l = i * 64 + lane;
                unsigned int m = (ctid[b * L_TEXT + l] == ct) &&
                                 (cdrid[b * L_TEXT + l] == rt) &&
                                 (tm[b * L_TEXT + l] != 0);
                tbits |= m << i;
            }
#pragma unroll
            for (int i = 0; i < 32; i++) {
                int n = i * 64 + lane;
                unsigned int m = (bct[b * N_TOKEN + n] == ct) &&
                                 (brt[b * N_TOKEN + n] == rt);
                pbits |= m << i;
            }
            int base = 0;
#pragma unroll
            for (int i = 0; i < 32; i++) {
                bool m = (tbits >> i) & 1;
                unsigned long long bal = __ballot(m);
                if (m) trowL[bp * L_TEXT + base + __popcll(bal & ltm)] = i * 64 + lane;
                base += __popcll(bal);
            }
            const int n_text = base;
            base = 0;
#pragma unroll
            for (int i = 0; i < 32; i++) {
                bool m = (pbits >> i) & 1;
                unsigned long long bal = __ballot(m);
                if (m) pidxL[bp * L_TEXT + base + __popcll(bal & ltm)] = i * 64 + lane;
                base += __popcll(bal);
            }
            const int n_prot = base;
            if (lane == 0) vcnt[bp] = n_text < n_prot ? n_text : n_prot;
        }
    }
    __threadfence();
    grid.sync();

    // ================= P1: prefix + deterministic scatter =================
    if (blockIdx.x < NPAIR) {
        const int bp = blockIdx.x;
        const int b = bp / 6;
        int base = 0, total = 0;
        for (int q = 0; q < NPAIR; q++) {
            int v = vcnt[q];
            if (q < bp) base += v;
            total += v;
        }
        if (bp == 0 && t == 0) *count = total < PM ? total : PM;
        const int v = vcnt[bp];
        for (int r = t; r < v; r += 256) {
            int g = base + r;
            if (g < PM) {
                rows_src[g] = b * L_TEXT + trowL[bp * L_TEXT + r];
                inv[b * N_TOKEN + pidxL[bp * L_TEXT + r]] = g;
            }
        }
    }
    __threadfence();
    grid.sync();

    int cnt = *(volatile const int*)count;
    if (cnt > PM) cnt = PM;

    const int lane = t & 63;
    const int w = t >> 6;
    const int wr = w >> 1, wc = w & 1;
    const int fr = lane & 15;
    const int kq = (lane >> 4) * 8;
    const int rj = (lane >> 4) * 4;

    // ================= P2: GEMM1 (fused gather, split-K=4) =================
    for (int u = blockIdx.x; u < (PM / 128) * (C_HID / 128) * KSPLIT; u += nb) {
        const int bx = u % (PM / 128);
        const int by = (u / (PM / 128)) % (C_HID / 128);
        const int bz = u / ((PM / 128) * (C_HID / 128));
        const int m0 = bx * 128;
        if (m0 >= cnt) continue;
        const int n0 = by * 128;
        const int kbeg = bz * KCHUNK;

        f32x4 acc[4][4];
#pragma unroll
        for (int i = 0; i < 4; i++)
#pragma unroll
            for (int j = 0; j < 4; j++) acc[i][j] = (f32x4){0.f, 0.f, 0.f, 0.f};

        const float* ap[2];
        const bf16_t* bp[2];
        int ofs[2];
        bool av[2];
#pragma unroll
        for (int j = 0; j < 2; j++) {
            int c = t + 256 * j;
            int row = c >> 2, c8 = (c & 3) * 8;
            av[j] = (m0 + row < cnt);
            ap[j] = X + (size_t)(av[j] ? rows_src[m0 + row] : 0) * C_TEXT + kbeg + c8;
            bp[j] = W1b + (size_t)(n0 + row) * C_TEXT + kbeg + c8;
            ofs[j] = row * 40 + c8;
        }
        const int BUF = 128 * 40;

        bf16x8 ra[2], rb[2];
#pragma unroll
        for (int j = 0; j < 2; j++) {
            bf16x8 val;
            if (av[j]) {
                float4 v0 = *(const float4*)(ap[j]);
                float4 v1 = *(const float4*)(ap[j] + 4);
                val[0] = (bf16_t)v0.x; val[1] = (bf16_t)v0.y; val[2] = (bf16_t)v0.z; val[3] = (bf16_t)v0.w;
                val[4] = (bf16_t)v1.x; val[5] = (bf16_t)v1.y; val[6] = (bf16_t)v1.z; val[7] = (bf16_t)v1.w;
            } else {
#pragma unroll
                for (int e = 0; e < 8; e++) val[e] = (bf16_t)0.0f;
            }
            ra[j] = val;
            rb[j] = *(const bf16x8*)(bp[j]);
        }

        const int T = KCHUNK / 32;   // 28
        for (int tile = 0; tile < T; ++tile) {
            const int cur = tile & 1;
#pragma unroll
            for (int j = 0; j < 2; j++) {
                *(bf16x8*)(AsF + cur * BUF + ofs[j]) = ra[j];
                *(bf16x8*)(BsF + cur * BUF + ofs[j]) = rb[j];
            }
            bf16x8 na[2], nbv[2];
            bool more = (tile + 1 < T);
            if (more) {
                int k = (tile + 1) * 32;
#pragma unroll
                for (int j = 0; j < 2; j++) {
                    bf16x8 val;
                    if (av[j]) {
                        float4 v0 = *(const float4*)(ap[j] + k);
                        float4 v1 = *(const float4*)(ap[j] + k + 4);
                        val[0] = (bf16_t)v0.x; val[1] = (bf16_t)v0.y; val[2] = (bf16_t)v0.z; val[3] = (bf16_t)v0.w;
                        val[4] = (bf16_t)v1.x; val[5] = (bf16_t)v1.y; val[6] = (bf16_t)v1.z; val[7] = (bf16_t)v1.w;
                    } else {
#pragma unroll
                        for (int e = 0; e < 8; e++) val[e] = (bf16_t)0.0f;
                    }
                    na[j] = val;
                    nbv[j] = *(const bf16x8*)(bp[j] + k);
                }
            }
            __syncthreads();
            bf16x8 af[4], bfr[4];
#pragma unroll
            for (int mi = 0; mi < 4; mi++)
                af[mi] = *(const bf16x8*)(AsF + cur * BUF + (wr * 64 + mi * 16 + fr) * 40 + kq);
#pragma unroll
            for (int ni = 0; ni < 4; ni++)
                bfr[ni] = *(const bf16x8*)(BsF + cur * BUF + (wc * 64 + ni * 16 + fr) * 40 + kq);
#pragma unroll
            for (int mi = 0; mi < 4; mi++)
#pragma unroll
                for (int ni = 0; ni < 4; ni++)
                    acc[mi][ni] = __builtin_amdgcn_mfma_f32_16x16x32_bf16(
                        af[mi], bfr[ni], acc[mi][ni], 0, 0, 0);
            if (more) {
#pragma unroll
                for (int j = 0; j < 2; j++) { ra[j] = na[j]; rb[j] = nbv[j]; }
            }
        }

        float* Pk = P + (size_t)bz * PM * C_HID;
#pragma unroll
        for (int mi = 0; mi < 4; mi++) {
#pragma unroll
            for (int ni = 0; ni < 4; ni++) {
                int gn = n0 + wc * 64 + ni * 16 + fr;
#pragma unroll
                for (int j = 0; j < 4; j++) {
                    int gm = m0 + wr * 64 + mi * 16 + rj + j;
                    if (gm < cnt) Pk[(size_t)gm * C_HID + gn] = acc[mi][ni][j];
                }
            }
        }
        __syncthreads();   // protect LDS reuse across u-iterations
    }
    __threadfence();
    grid.sync();

    // ================= P3: reduce + bias + SiLU -> H =================
    for (int u = blockIdx.x; u < (PM * C_HID / 4) / 256; u += nb) {
        int idx = u * 256 + t;
        int m = idx / (C_HID / 4);
        int c = (idx % (C_HID / 4)) * 4;
        if (m < cnt) {
            f32x4 s = *(const f32x4*)(P + (size_t)m * C_HID + c);
#pragma unroll
            for (int ks = 1; ks < KSPLIT; ks++)
                s += *(const f32x4*)(P + ((size_t)ks * PM + m) * C_HID + c);
            f32x4 bb = *(const f32x4*)(b1 + c);
            bf16x4 o;
#pragma unroll
            for (int j = 0; j < 4; j++) {
                float v = s[j] + bb[j];
                o[j] = (bf16_t)(v / (1.0f + __expf(-v)));
            }
            *(bf16x4*)(H + (size_t)m * C_HID + c) = o;
        }
    }
    __threadfence();
    grid.sync();

    // ================= P4: GEMM2 (split-K=4) -> P (reused) =================
    for (int u = blockIdx.x; u < (PM / 64) * (C_OUT / 128) * KSPLIT2; u += nb) {
        const int bx = u % (PM / 64);
        const int by = (u / (PM / 64)) % (C_OUT / 128);
        const int bz = u / ((PM / 64) * (C_OUT / 128));
        const int m0 = bx * 64;
        if (m0 >= cnt) continue;
        const int n0 = by * 128;
        const int kbeg = bz * KCHUNK2;

        f32x4 acc[2][4];
#pragma unroll
        for (int i = 0; i < 2; i++)
#pragma unroll
            for (int j = 0; j < 4; j++) acc[i][j] = (f32x4){0.f, 0.f, 0.f, 0.f};

        const int arow = t >> 2, ac8 = (t & 3) * 8;
        const bf16_t* ap = H + (size_t)(m0 + arow) * C_HID + kbeg + ac8;
        const int aofs = arow * 40 + ac8;
        const bf16_t* bp[2];
        int bofs[2];
#pragma unroll
        for (int j = 0; j < 2; j++) {
            int c = t + 256 * j;
            int row = c >> 2, c8 = (c & 3) * 8;
            bp[j] = W2b + (size_t)(n0 + row) * C_HID + kbeg + c8;
            bofs[j] = row * 40 + c8;
        }
        const int ABUF = 64 * 40, BBUF = 128 * 40;

        bf16x8 ra = *(const bf16x8*)(ap);
        bf16x8 rb0 = *(const bf16x8*)(bp[0]);
        bf16x8 rb1 = *(const bf16x8*)(bp[1]);

        const int T = KCHUNK2 / 32;   // 6
        for (int tile = 0; tile < T; ++tile) {
            const int cur = tile & 1;
            *(bf16x8*)(AsF + cur * ABUF + aofs) = ra;
            *(bf16x8*)(BsF + cur * BBUF + bofs[0]) = rb0;
            *(bf16x8*)(BsF + cur * BBUF + bofs[1]) = rb1;
            bf16x8 na, nb0, nb1;
            bool more = (tile + 1 < T);
            if (more) {
                int k = (tile + 1) * 32;
                na = *(const bf16x8*)(ap + k);
                nb0 = *(const bf16x8*)(bp[0] + k);
                nb1 = *(const bf16x8*)(bp[1] + k);
            }
            __syncthreads();
            bf16x8 af[2], bfr[4];
#pragma unroll
            for (int mi = 0; mi < 2; mi++)
                af[mi] = *(const bf16x8*)(AsF + cur * ABUF + (wr * 32 + mi * 16 + fr) * 40 + kq);
#pragma unroll
            for (int ni = 0; ni < 4; ni++)
                bfr[ni] = *(const bf16x8*)(BsF + cur * BBUF + (wc * 64 + ni * 16 + fr) * 40 + kq);
#pragma unroll
            for (int mi = 0; mi < 2; mi++)
#pragma unroll
                for (int ni = 0; ni < 4; ni++)
                    acc[mi][ni] = __builtin_amdgcn_mfma_f32_16x16x32_bf16(
                        af[mi], bfr[ni], acc[mi][ni], 0, 0, 0);
            if (more) { ra = na; rb0 = nb0; rb1 = nb1; }
        }

        float* Pk = P + (size_t)bz * PM * C_OUT;
#pragma unroll
        for (int mi = 0; mi < 2; mi++) {
#pragma unroll
            for (int ni = 0; ni < 4; ni++) {
                int gn = n0 + wc * 64 + ni * 16 + fr;
#pragma unroll
                for (int j = 0; j < 4; j++) {
                    int gm = m0 + wr * 32 + mi * 16 + rj + j;
                    if (gm < cnt) Pk[(size_t)gm * C_OUT + gn] = acc[mi][ni][j];
                }
            }
        }
        __syncthreads();
    }
    __threadfence();
    grid.sync();

    // ================= P5: full-output scatter/zero =================
    const float sc = scale[0];
    for (int u = blockIdx.x; u < (MAXROWS * C_OUT / 4) / 256; u += nb) {
        int idx = u * 256 + t;
        int token = idx / (C_OUT / 4);
        int c = (idx % (C_OUT / 4)) * 4;
        int m = inv[token];
        f32x4 o = (f32x4){0.f, 0.f, 0.f, 0.f};
        if (m >= 0) {
            f32x4 s = *(const f32x4*)(P + (size_t)m * C_OUT + c);
#pragma unroll
            for (int ks = 1; ks < KSPLIT2; ks++)
                s += *(const f32x4*)(P + ((size_t)ks * PM + m) * C_OUT + c);
            f32x4 bb = *(const f32x4*)(b2 + c);
#pragma unroll
            for (int j = 0; j < 4; j++) o[j] = sc * (s[j] + bb[j]);
        }
        *(f32x4*)(outp + (size_t)token * C_OUT + c) = o;
    }
}

// ============================================================================
//                  FALLBACK: R6 multi-kernel pipeline (known-good)
// ============================================================================
__global__ __launch_bounds__(256) void init_map_kernel(
    const float* __restrict__ W1, const float* __restrict__ W2,
    bf16_t* __restrict__ W1b, bf16_t* __restrict__ W2b,
    int* __restrict__ inv,
    const int* __restrict__ tm, const int* __restrict__ ctid,
    const int* __restrict__ cdrid, const int* __restrict__ bct,
    const int* __restrict__ brt,
    int* __restrict__ trowL, int* __restrict__ pidxL, int* __restrict__ vcnt) {
    if (blockIdx.x >= CVT_BLOCKS) {
        const int bp = blockIdx.x - CVT_BLOCKS;
        const int lane = threadIdx.x;
        if (lane >= 64) return;
        const int b = bp / 6, p = bp % 6;
        const int ct = (p < 3) ? 1 : 2;
        const int rt = 2 + 2 * (p % 3);
        const unsigned long long ltm = (1ull << lane) - 1ull;

        unsigned int tbits = 0, pbits = 0;
#pragma unroll
        for (int i = 0; i < 32; i++) {
            int l = i * 64 + lane;
            unsigned int m = (ctid[b * L_TEXT + l] == ct) &&
                             (cdrid[b * L_TEXT + l] == rt) &&
                             (tm[b * L_TEXT + l] != 0);
            tbits |= m << i;
        }
#pragma unroll
        for (int i = 0; i < 32; i++) {
            int n = i * 64 + lane;
            unsigned int m = (bct[b * N_TOKEN + n] == ct) &&
                             (brt[b * N_TOKEN + n] == rt);
            pbits |= m << i;
        }
        int base = 0;
#pragma unroll
        for (int i = 0; i < 32; i++) {
            bool m = (tbits >> i) & 1;
            unsigned long long bal = __ballot(m);
            if (m) trowL[bp * L_TEXT + base + __popcll(bal & ltm)] = i * 64 + lane;
            base += __popcll(bal);
        }
        const int n_text = base;
        base = 0;
#pragma unroll
        for (int i = 0; i < 32; i++) {
            bool m = (pbits >> i) & 1;
            unsigned long long bal = __ballot(m);
            if (m) pidxL[bp * L_TEXT + base + __popcll(bal & ltm)] = i * 64 + lane;
            base += __popcll(bal);
        }
        const int n_prot = base;
        if (lane == 0) vcnt[bp] = n_text < n_prot ? n_text : n_prot;
        return;
    }
    int idx = blockIdx.x * 256 + threadIdx.x;
    if (idx < NW1) {
        int i = idx * 8;
        float4 v0 = *(const float4*)(W1 + i);
        float4 v1 = *(const float4*)(W1 + i + 4);
        bf16x8 o;
        o[0] = (bf16_t)v0.x; o[1] = (bf16_t)v0.y; o[2] = (bf16_t)v0.z; o[3] = (bf16_t)v0.w;
        o[4] = (bf16_t)v1.x; o[5] = (bf16_t)v1.y; o[6] = (bf16_t)v1.z; o[7] = (bf16_t)v1.w;
        *(bf16x8*)(W1b + i) = o;
    } else if (idx < NW1 + NW2) {
        int i = (idx - NW1) * 8;
        float4 v0 = *(const float4*)(W2 + i);
        float4 v1 = *(const float4*)(W2 + i + 4);
        bf16x8 o;
        o[0] = (bf16_t)v0.x; o[1] = (bf16_t)v0.y; o[2] = (bf16_t)v0.z; o[3] = (bf16_t)v0.w;
        o[4] = (bf16_t)v1.x; o[5] = (bf16_t)v1.y; o[6] = (bf16_t)v1.z; o[7] = (bf16_t)v1.w;
        *(bf16x8*)(W2b + i) = o;
    } else {
        int i = idx - NW1 - NW2;
        int4 m1 = {-1, -1, -1, -1};
        ((int4*)inv)[i] = m1;
    }
}

__global__ __launch_bounds__(64) void map_write_kernel(
    const int* __restrict__ trowL, const int* __restrict__ pidxL,
    const int* __restrict__ vcnt,
    int* __restrict__ rows_src, int* __restrict__ inv, int* __restrict__ count) {
    const int bp = blockIdx.x;
    const int b = bp / 6;
    const int lane = threadIdx.x;
    int base = 0, total = 0;
    for (int q = 0; q < NPAIR; q++) {
        int v = vcnt[q];
        if (q < bp) base += v;
        total += v;
    }
    if (bp == 0 && lane == 0) *count = total < PM ? total : PM;
    const int v = vcnt[bp];
    for (int r = lane; r < v; r += 64) {
        int g = base + r;
        if (g < PM) {
            rows_src[g] = b * L_TEXT + trowL[bp * L_TEXT + r];
            inv[b * N_TOKEN + pidxL[bp * L_TEXT + r]] = g;
        }
    }
}

__global__ __launch_bounds__(256) void gather_kernel(
    const float* __restrict__ X, const int* __restrict__ rows_src,
    const int* __restrict__ countp, bf16_t* __restrict__ Xg) {
    int count = *countp; if (count > PM) count = PM;
    int idx = blockIdx.x * 256 + threadIdx.x;
    int m = idx / GCH;
    if (m >= count) return;
    int c = (idx % GCH) * 8;
    const float* src = X + (size_t)rows_src[m] * C_TEXT + c;
    float4 v0 = *(const float4*)(src);
    float4 v1 = *(const float4*)(src + 4);
    bf16x8 o;
    o[0] = (bf16_t)v0.x; o[1] = (bf16_t)v0.y; o[2] = (bf16_t)v0.z; o[3] = (bf16_t)v0.w;
    o[4] = (bf16_t)v1.x; o[5] = (bf16_t)v1.y; o[6] = (bf16_t)v1.z; o[7] = (bf16_t)v1.w;
    *(bf16x8*)(Xg + (size_t)m * C_TEXT + c) = o;
}

__global__ __launch_bounds__(256) void gemm1_kernel(
    const bf16_t* __restrict__ Xg, const bf16_t* __restrict__ W1b,
    const int* __restrict__ countp, float* __restrict__ P) {
    int count = *countp; if (count > PM) count = PM;
    const int m0 = blockIdx.x * 128;
    if (m0 >= count) return;
    const int n0 = blockIdx.y * 128;
    const int kbeg = blockIdx.z * KCHUNK;

    __shared__ __align__(16) bf16_t As[2][128][40];
    __shared__ __align__(16) bf16_t Bs[2][128][40];

    const int t = threadIdx.x;
    const int lane = t & 63;
    const int w = t >> 6;
    const int wr = w >> 1, wc = w & 1;
    const int fr = lane & 15;
    const int kq = (lane >> 4) * 8;

    f32x4 acc[4][4];
#pragma unroll
    for (int i = 0; i < 4; i++)
#pragma unroll
        for (int j = 0; j < 4; j++) acc[i][j] = (f32x4){0.f, 0.f, 0.f, 0.f};

    const bf16_t* ap[2];
    const bf16_t* bp[2];
    int ofs[2];
#pragma unroll
    for (int j = 0; j < 2; j++) {
        int c = t + 256 * j;
        int row = c >> 2, c8 = (c & 3) * 8;
        ap[j] = Xg + (size_t)(m0 + row) * C_TEXT + kbeg + c8;
        bp[j] = W1b + (size_t)(n0 + row) * C_TEXT + kbeg + c8;
        ofs[j] = row * 40 + c8;
    }

    bf16_t* AsF = &As[0][0][0];
    bf16_t* BsF = &Bs[0][0][0];
    const int BUF = 128 * 40;

    bf16x8 ra[2], rb[2];
#pragma unroll
    for (int j = 0; j < 2; j++) { ra[j] = *(const bf16x8*)(ap[j]); rb[j] = *(const bf16x8*)(bp[j]); }

    const int T = KCHUNK / 32;
    for (int tile = 0; tile < T; ++tile) {
        const int cur = tile & 1;
#pragma unroll
        for (int j = 0; j < 2; j++) {
            *(bf16x8*)(AsF + cur * BUF + ofs[j]) = ra[j];
            *(bf16x8*)(BsF + cur * BUF + ofs[j]) = rb[j];
        }
        bf16x8 na[2], nb[2];
        bool more = (tile + 1 < T);
        if (more) {
            int k = (tile + 1) * 32;
#pragma unroll
            for (int j = 0; j < 2; j++) {
                na[j] = *(const bf16x8*)(ap[j] + k);
                nb[j] = *(const bf16x8*)(bp[j] + k);
            }
        }
        __syncthreads();
        bf16x8 af[4], bfr[4];
#pragma unroll
        for (int mi = 0; mi < 4; mi++)
            af[mi] = *(const bf16x8*)(AsF + cur * BUF + (wr * 64 + mi * 16 + fr) * 40 + kq);
#pragma unroll
        for (int ni = 0; ni < 4; ni++)
            bfr[ni] = *(const bf16x8*)(BsF + cur * BUF + (wc * 64 + ni * 16 + fr) * 40 + kq);
#pragma unroll
        for (int mi = 0; mi < 4; mi++)
#pragma unroll
            for (int ni = 0; ni < 4; ni++)
                acc[mi][ni] = __builtin_amdgcn_mfma_f32_16x16x32_bf16(
                    af[mi], bfr[ni], acc[mi][ni], 0, 0, 0);
        if (more) {
#pragma unroll
            for (int j = 0; j < 2; j++) { ra[j] = na[j]; rb[j] = nb[j]; }
        }
    }

    float* Pk = P + (size_t)blockIdx.z * PM * C_HID;
    const int rj = (lane >> 4) * 4;
#pragma unroll
    for (int mi = 0; mi < 4; mi++) {
#pragma unroll
        for (int ni = 0; ni < 4; ni++) {
            int gn = n0 + wc * 64 + ni * 16 + fr;
#pragma unroll
            for (int j = 0; j < 4; j++) {
                int gm = m0 + wr * 64 + mi * 16 + rj + j;
                if (gm < count) Pk[(size_t)gm * C_HID + gn] = acc[mi][ni][j];
            }
        }
    }
}

__global__ __launch_bounds__(256) void reduce1_kernel(
    const float* __restrict__ P, const float* __restrict__ b1,
    const int* __restrict__ countp, bf16_t* __restrict__ H) {
    int count = *countp; if (count > PM) count = PM;
    int idx = blockIdx.x * 256 + threadIdx.x;
    int m = idx / (C_HID / 4);
    int c = (idx % (C_HID / 4)) * 4;
    if (m >= count) return;
    f32x4 s = *(const f32x4*)(P + (size_t)m * C_HID + c);
#pragma unroll
    for (int ks = 1; ks < KSPLIT; ks++)
        s += *(const f32x4*)(P + ((size_t)ks * PM + m) * C_HID + c);
    f32x4 bb = *(const f32x4*)(b1 + c);
    bf16x4 o;
#pragma unroll
    for (int j = 0; j < 4; j++) {
        float v = s[j] + bb[j];
        o[j] = (bf16_t)(v / (1.0f + __expf(-v)));
    }
    *(bf16x4*)(H + (size_t)m * C_HID + c) = o;
}

__global__ __launch_bounds__(256) void gemm2_kernel(
    const bf16_t* __restrict__ Hm, const bf16_t* __restrict__ W2b,
    const int* __restrict__ countp, float* __restrict__ P2) {
    int count = *countp; if (count > PM) count = PM;
    const int m0 = blockIdx.x * 64;
    if (m0 >= count) return;
    const int n0 = blockIdx.y * 128;
    const int kbeg = blockIdx.z * KCHUNK2F;

    __shared__ __align__(16) bf16_t As[2][64][40];
    __shared__ __align__(16) bf16_t Bs[2][128][40];

    const int t = threadIdx.x;
    const int lane = t & 63;
    const int w = t >> 6;
    const int wr = w >> 1, wc = w & 1;
    const int fr = lane & 15;
    const int kq = (lane >> 4) * 8;

    f32x4 acc[2][4];
#pragma unroll
    for (int i = 0; i < 2; i++)
#pragma unroll
        for (int j = 0; j < 4; j++) acc[i][j] = (f32x4){0.f, 0.f, 0.f, 0.f};

    const int arow = t >> 2, ac8 = (t & 3) * 8;
    const bf16_t* ap = Hm + (size_t)(m0 + arow) * C_HID + kbeg + ac8;
    const int aofs = arow * 40 + ac8;
    const bf16_t* bp[2];
    int bofs[2];
#pragma unroll
    for (int j = 0; j < 2; j++) {
        int c = t + 256 * j;
        int row = c >> 2, c8 = (c & 3) * 8;
        bp[j] = W2b + (size_t)(n0 + row) * C_HID + kbeg + c8;
        bofs[j] = row * 40 + c8;
    }

    bf16_t* AsF = &As[0][0][0];
    bf16_t* BsF = &Bs[0][0][0];
    const int ABUF = 64 * 40, BBUF = 128 * 40;

    bf16x8 ra = *(const bf16x8*)(ap);
    bf16x8 rb0 = *(const bf16x8*)(bp[0]);
    bf16x8 rb1 = *(const bf16x8*)(bp[1]);

    const int T = KCHUNK2F / 32;
    for (int tile = 0; tile < T; ++tile) {
        const int cur = tile & 1;
        *(bf16x8*)(AsF + cur * ABUF + aofs) = ra;
        *(bf16x8*)(BsF + cur * BBUF + bofs[0]) = rb0;
        *(bf16x8*)(BsF + cur * BBUF + bofs[1]) = rb1;
        bf16x8 na, nb0, nb1;
        bool more = (tile + 1 < T);
        if (more) {
            int k = (tile + 1) * 32;
            na = *(const bf16x8*)(ap + k);
            nb0 = *(const bf16x8*)(bp[0] + k);
            nb1 = *(const bf16x8*)(bp[1] + k);
        }
        __syncthreads();
        bf16x8 af[2], bfr[4];
#pragma unroll
        for (int mi = 0; mi < 2; mi++)
            af[mi] = *(const bf16x8*)(AsF + cur * ABUF + (wr * 32 + mi * 16 + fr) * 40 + kq);
#pragma unroll
        for (int ni = 0; ni < 4; ni++)
            bfr[ni] = *(const bf16x8*)(BsF + cur * BBUF + (wc * 64 + ni * 16 + fr) * 40 + kq);
#pragma unroll
        for (int mi = 0; mi < 2; mi++)
#pragma unroll
            for (int ni = 0; ni < 4; ni++)
                acc[mi][ni] = __builtin_amdgcn_mfma_f32_16x16x32_bf16(
                    af[mi], bfr[ni], acc[mi][ni], 0, 0, 0);
        if (more) { ra = na; rb0 = nb0; rb1 = nb1; }
    }

    float* Pk = P2 + (size_t)blockIdx.z * PM * C_OUT;
    const int rj = (lane >> 4) * 4;
#pragma unroll
    for (int mi = 0; mi < 2; mi++) {
#pragma unroll
        for (int ni = 0; ni < 4; ni++) {
            int gn = n0 + wc * 64 + ni * 16 + fr;
#pragma unroll
            for (int j = 0; j < 4; j++) {
                int gm = m0 + wr * 32 + mi * 16 + rj + j;
                if (gm < count) Pk[(size_t)gm * C_OUT + gn] = acc[mi][ni][j];
            }
        }
    }
}

__global__ __launch_bounds__(256) void out_kernel(
    const float* __restrict__ P2, const float* __restrict__ b2,
    const int* __restrict__ inv, const float* __restrict__ scale,
    float* __restrict__ out) {
    int idx = blockIdx.x * 256 + threadIdx.x;
    int token = idx / (C_OUT / 4);
    int c = (idx % (C_OUT / 4)) * 4;
    int m = inv[token];
    f32x4 o = (f32x4){0.f, 0.f, 0.f, 0.f};
    if (m >= 0) {
        f32x4 s = *(const f32x4*)(P2 + (size_t)m * C_OUT + c);
#pragma unroll
        for (int ks = 1; ks < KSPLIT2F; ks++)
            s += *(const f32x4*)(P2 + ((size_t)ks * PM + m) * C_OUT + c);
        f32x4 bb = *(const f32x4*)(b2 + c);
        const float sc = scale[0];
#pragma unroll
        for (int j = 0; j < 4; j++) o[j] = sc * (s[j] + bb[j]);
    }
    *(f32x4*)(out + (size_t)token * C_OUT + c) = o;
}

// ---------------------------------------------------------------------------
extern "C" void kernel_launch(void* const* d_in, const int* in_sizes, int n_in,
                              void* d_out, int out_size, void* d_ws, size_t ws_size,
                              hipStream_t stream) {
    const float* X     = (const float*)d_in[0];
    const int*   tm    = (const int*)d_in[1];
    const int*   ctid  = (const int*)d_in[2];
    const int*   cdrid = (const int*)d_in[3];
    const int*   bct   = (const int*)d_in[4];
    const int*   brt   = (const int*)d_in[5];
    const float* W1    = (const float*)d_in[6];
    const float* b1    = (const float*)d_in[7];
    const float* W2    = (const float*)d_in[8];
    const float* b2    = (const float*)d_in[9];
    const float* scale = (const float*)d_in[10];

    char* ws = (char*)d_ws;
    size_t off = 0;
    int* count = (int*)(ws + off);        off += 1024;
    int* vcnt = (int*)(ws + off);         off += 1024;
    int* rows_src = (int*)(ws + off);     off += (size_t)PM * 4;
    int* inv = (int*)(ws + off);          off += (size_t)MAXROWS * 4;
    int* trowL = (int*)(ws + off);        off += (size_t)NPAIR * L_TEXT * 4;
    int* pidxL = (int*)(ws + off);        off += (size_t)NPAIR * L_TEXT * 4;
    bf16_t* W1b = (bf16_t*)(ws + off);    off += (size_t)C_HID * C_TEXT * 2;
    bf16_t* W2b = (bf16_t*)(ws + off);    off += (size_t)C_OUT * C_HID * 2;
    bf16_t* Xg = (bf16_t*)(ws + off);     off += (size_t)PM * C_TEXT * 2;
    bf16_t* H = (bf16_t*)(ws + off);      off += (size_t)PM * C_HID * 2;
    float* P = (float*)(ws + off);        off += (size_t)KSPLIT * PM * C_HID * 4;
    float* outp = (float*)d_out;

    // occupancy-sized cooperative launch (deterministic; query is capture-safe)
    int maxb = 0;
    hipError_t qe = hipOccupancyMaxActiveBlocksPerMultiprocessor(
        &maxb, (const void*)mega_kernel, 256, 0);

    if (qe == hipSuccess && maxb >= 1) {
        int grid = 256 * maxb;
        if (grid > 768) grid = 768;
        void* args[] = {(void*)&X, (void*)&tm, (void*)&ctid, (void*)&cdrid,
                        (void*)&bct, (void*)&brt, (void*)&W1, (void*)&b1,
                        (void*)&W2, (void*)&b2, (void*)&scale,
                        (void*)&W1b, (void*)&W2b, (void*)&inv, (void*)&count,
                        (void*)&vcnt, (void*)&rows_src, (void*)&trowL,
                        (void*)&pidxL, (void*)&H, (void*)&P, (void*)&outp};
        hipLaunchCooperativeKernel((const void*)mega_kernel, dim3(grid),
                                   dim3(256), args, 0, stream);
        return;
    }

    // fallback: proven R6 pipeline
    init_map_kernel<<<CVT_BLOCKS + NPAIR, 256, 0, stream>>>(
        W1, W2, W1b, W2b, inv, tm, ctid, cdrid, bct, brt, trowL, pidxL, vcnt);
    map_write_kernel<<<NPAIR, 64, 0, stream>>>(trowL, pidxL, vcnt,
                                               rows_src, inv, count);
    gather_kernel<<<(PM * GCH) / 256, 256, 0, stream>>>(X, rows_src, count, Xg);
    dim3 g1(PM / 128, C_HID / 128, KSPLIT);
    gemm1_kernel<<<g1, 256, 0, stream>>>(Xg, W1b, count, P);
    reduce1_kernel<<<(PM * C_HID / 4) / 256, 256, 0, stream>>>(P, b1, count, H);
    dim3 g2(PM / 64, C_OUT / 128, KSPLIT2F);
    gemm2_kernel<<<g2, 256, 0, stream>>>(H, W2b, count, P);
    out_kernel<<<(MAXROWS * C_OUT / 4) / 256, 256, 0, stream>>>(
        P, b2, inv, scale, (float*)d_out);
}

// Round 9
// 142.821 us; speedup vs baseline: 3.0813x; 3.0813x over previous
//
#include <hip/hip_runtime.h>
#include <hip/hip_bf16.h>
#include <math.h>

typedef __bf16 bf16_t;
typedef bf16_t bf16x8 __attribute__((ext_vector_type(8)));
typedef bf16_t bf16x4 __attribute__((ext_vector_type(4)));
typedef float f32x4 __attribute__((ext_vector_type(4)));

#define L_TEXT 2048
#define N_TOKEN 2048
#define C_TEXT 3584
#define C_OUT 384
#define C_HID 768
#define BATCH 8
#define MAXROWS (BATCH * N_TOKEN)
#define PM 3072            // capacity for compacted rows (count ~2400)
#define NPAIR (BATCH * 6)

#define NW1 (C_HID * C_TEXT / 8)          // 344064 W1 cvt chunks
#define NW2 (C_OUT * C_HID / 8)           // 36864  W2 cvt chunks
#define NZERO (MAXROWS * C_OUT / 4)       // 1572864 f32x4 zero chunks of d_out
#define CHUNKS_TOTAL (NW1 + NW2 + NZERO)  // 1953792
#define CHUNK_BLOCKS (CHUNKS_TOTAL / 256) // 7632 exactly
#define GCH (C_TEXT / 8)                  // 448 chunks per gathered row

// ---------------------------------------------------------------------------
// init node: W1/W2 fp32->bf16 + zero d_out + 48 per-pair mask-scan blocks
__global__ __launch_bounds__(256) void init_map_kernel(
    const float* __restrict__ W1, const float* __restrict__ W2,
    bf16_t* __restrict__ W1b, bf16_t* __restrict__ W2b,
    float* __restrict__ outp,
    const int* __restrict__ tm, const int* __restrict__ ctid,
    const int* __restrict__ cdrid, const int* __restrict__ bct,
    const int* __restrict__ brt,
    int* __restrict__ trowL, int* __restrict__ pidxL, int* __restrict__ vcnt) {
    if (blockIdx.x >= CHUNK_BLOCKS) {
        // ---- mask scan for pair bp (one wave) ----
        const int bp = blockIdx.x - CHUNK_BLOCKS;
        const int lane = threadIdx.x;
        if (lane >= 64) return;
        const int b = bp / 6, p = bp % 6;
        const int ct = (p < 3) ? 1 : 2;
        const int rt = 2 + 2 * (p % 3);
        const unsigned long long ltm = (1ull << lane) - 1ull;

        unsigned int tbits = 0, pbits = 0;
#pragma unroll
        for (int i = 0; i < 32; i++) {
            int l = i * 64 + lane;
            unsigned int m = (ctid[b * L_TEXT + l] == ct) &&
                             (cdrid[b * L_TEXT + l] == rt) &&
                             (tm[b * L_TEXT + l] != 0);
            tbits |= m << i;
        }
#pragma unroll
        for (int i = 0; i < 32; i++) {
            int n = i * 64 + lane;
            unsigned int m = (bct[b * N_TOKEN + n] == ct) &&
                             (brt[b * N_TOKEN + n] == rt);
            pbits |= m << i;
        }
        int base = 0;
#pragma unroll
        for (int i = 0; i < 32; i++) {
            bool m = (tbits >> i) & 1;
            unsigned long long bal = __ballot(m);
            if (m) trowL[bp * L_TEXT + base + __popcll(bal & ltm)] = i * 64 + lane;
            base += __popcll(bal);
        }
        const int n_text = base;
        base = 0;
#pragma unroll
        for (int i = 0; i < 32; i++) {
            bool m = (pbits >> i) & 1;
            unsigned long long bal = __ballot(m);
            if (m) pidxL[bp * L_TEXT + base + __popcll(bal & ltm)] = i * 64 + lane;
            base += __popcll(bal);
        }
        const int n_prot = base;
        if (lane == 0) vcnt[bp] = n_text < n_prot ? n_text : n_prot;
        return;
    }
    int idx = blockIdx.x * 256 + threadIdx.x;
    if (idx < NW1) {
        int i = idx * 8;
        float4 v0 = *(const float4*)(W1 + i);
        float4 v1 = *(const float4*)(W1 + i + 4);
        bf16x8 o;
        o[0] = (bf16_t)v0.x; o[1] = (bf16_t)v0.y; o[2] = (bf16_t)v0.z; o[3] = (bf16_t)v0.w;
        o[4] = (bf16_t)v1.x; o[5] = (bf16_t)v1.y; o[6] = (bf16_t)v1.z; o[7] = (bf16_t)v1.w;
        *(bf16x8*)(W1b + i) = o;
    } else if (idx < NW1 + NW2) {
        int i = (idx - NW1) * 8;
        float4 v0 = *(const float4*)(W2 + i);
        float4 v1 = *(const float4*)(W2 + i + 4);
        bf16x8 o;
        o[0] = (bf16_t)v0.x; o[1] = (bf16_t)v0.y; o[2] = (bf16_t)v0.z; o[3] = (bf16_t)v0.w;
        o[4] = (bf16_t)v1.x; o[5] = (bf16_t)v1.y; o[6] = (bf16_t)v1.z; o[7] = (bf16_t)v1.w;
        *(bf16x8*)(W2b + i) = o;
    } else {
        int z = idx - NW1 - NW2;          // < NZERO by construction
        f32x4 zv = (f32x4){0.f, 0.f, 0.f, 0.f};
        *(f32x4*)(outp + (size_t)z * 4) = zv;
    }
}

// ---------------------------------------------------------------------------
// prefix over 48 per-pair counts + deterministic scatter (no atomics)
__global__ __launch_bounds__(64) void map_write_kernel(
    const int* __restrict__ trowL, const int* __restrict__ pidxL,
    const int* __restrict__ vcnt,
    int* __restrict__ rows_src, int* __restrict__ rows_dst,
    int* __restrict__ count) {
    const int bp = blockIdx.x;
    const int b = bp / 6;
    const int lane = threadIdx.x;
    int base = 0, total = 0;
    for (int q = 0; q < NPAIR; q++) {
        int v = vcnt[q];
        if (q < bp) base += v;
        total += v;
    }
    if (bp == 0 && lane == 0) *count = total < PM ? total : PM;
    const int v = vcnt[bp];
    for (int r = lane; r < v; r += 64) {
        int g = base + r;
        if (g < PM) {
            rows_src[g] = b * L_TEXT + trowL[bp * L_TEXT + r];
            rows_dst[g] = b * N_TOKEN + pidxL[bp * L_TEXT + r];
        }
    }
}

// ---------------------------------------------------------------------------
// gather + fp32->bf16 convert of the compacted X rows
__global__ __launch_bounds__(256) void gather_kernel(
    const float* __restrict__ X, const int* __restrict__ rows_src,
    const int* __restrict__ countp, bf16_t* __restrict__ Xg) {
    int count = *countp; if (count > PM) count = PM;
    int idx = blockIdx.x * 256 + threadIdx.x;
    int m = idx / GCH;
    if (m >= count) return;
    int c = (idx % GCH) * 8;
    const float* src = X + (size_t)rows_src[m] * C_TEXT + c;
    float4 v0 = *(const float4*)(src);
    float4 v1 = *(const float4*)(src + 4);
    bf16x8 o;
    o[0] = (bf16_t)v0.x; o[1] = (bf16_t)v0.y; o[2] = (bf16_t)v0.z; o[3] = (bf16_t)v0.w;
    o[4] = (bf16_t)v1.x; o[5] = (bf16_t)v1.y; o[6] = (bf16_t)v1.z; o[7] = (bf16_t)v1.w;
    *(bf16x8*)(Xg + (size_t)m * C_TEXT + c) = o;
}

// ---------------------------------------------------------------------------
// GEMM1 fused: H[m][n] = silu(sum_K Xg[m][k]*W1[n][k] + b1[n])  (no split-K)
// 64x128 tile, BK=32, 4 waves (2x2), wave tile 32x64 (2x4 frags), dbuf LDS.
__global__ __launch_bounds__(256) void gemm1_kernel(
    const bf16_t* __restrict__ Xg, const bf16_t* __restrict__ W1b,
    const float* __restrict__ b1, const int* __restrict__ countp,
    bf16_t* __restrict__ H) {
    int count = *countp; if (count > PM) count = PM;
    const int m0 = blockIdx.x * 64;
    if (m0 >= count) return;
    const int n0 = blockIdx.y * 128;

    __shared__ __align__(16) bf16_t As[2][64][40];
    __shared__ __align__(16) bf16_t Bs[2][128][40];

    const int t = threadIdx.x;
    const int lane = t & 63;
    const int w = t >> 6;
    const int wr = w >> 1, wc = w & 1;
    const int fr = lane & 15;
    const int kq = (lane >> 4) * 8;

    f32x4 acc[2][4];
#pragma unroll
    for (int i = 0; i < 2; i++)
#pragma unroll
        for (int j = 0; j < 4; j++) acc[i][j] = (f32x4){0.f, 0.f, 0.f, 0.f};

    const int arow = t >> 2, ac8 = (t & 3) * 8;
    const bf16_t* ap = Xg + (size_t)(m0 + arow) * C_TEXT + ac8;  // stale rows harmless
    const int aofs = arow * 40 + ac8;
    const bf16_t* bp[2];
    int bofs[2];
#pragma unroll
    for (int j = 0; j < 2; j++) {
        int c = t + 256 * j;
        int row = c >> 2, c8 = (c & 3) * 8;
        bp[j] = W1b + (size_t)(n0 + row) * C_TEXT + c8;
        bofs[j] = row * 40 + c8;
    }

    bf16_t* AsF = &As[0][0][0];
    bf16_t* BsF = &Bs[0][0][0];
    const int ABUF = 64 * 40, BBUF = 128 * 40;

    bf16x8 ra = *(const bf16x8*)(ap);
    bf16x8 rb0 = *(const bf16x8*)(bp[0]);
    bf16x8 rb1 = *(const bf16x8*)(bp[1]);

    const int T = C_TEXT / 32;   // 112
    for (int tile = 0; tile < T; ++tile) {
        const int cur = tile & 1;
        *(bf16x8*)(AsF + cur * ABUF + aofs) = ra;
        *(bf16x8*)(BsF + cur * BBUF + bofs[0]) = rb0;
        *(bf16x8*)(BsF + cur * BBUF + bofs[1]) = rb1;
        bf16x8 na, nb0, nb1;
        bool more = (tile + 1 < T);
        if (more) {
            int k = (tile + 1) * 32;
            na = *(const bf16x8*)(ap + k);
            nb0 = *(const bf16x8*)(bp[0] + k);
            nb1 = *(const bf16x8*)(bp[1] + k);
        }
        __syncthreads();
        bf16x8 af[2], bfr[4];
#pragma unroll
        for (int mi = 0; mi < 2; mi++)
            af[mi] = *(const bf16x8*)(AsF + cur * ABUF + (wr * 32 + mi * 16 + fr) * 40 + kq);
#pragma unroll
        for (int ni = 0; ni < 4; ni++)
            bfr[ni] = *(const bf16x8*)(BsF + cur * BBUF + (wc * 64 + ni * 16 + fr) * 40 + kq);
#pragma unroll
        for (int mi = 0; mi < 2; mi++)
#pragma unroll
            for (int ni = 0; ni < 4; ni++)
                acc[mi][ni] = __builtin_amdgcn_mfma_f32_16x16x32_bf16(
                    af[mi], bfr[ni], acc[mi][ni], 0, 0, 0);
        if (more) { ra = na; rb0 = nb0; rb1 = nb1; }
        __syncthreads();
    }

    const int rj = (lane >> 4) * 4;
#pragma unroll
    for (int mi = 0; mi < 2; mi++) {
#pragma unroll
        for (int ni = 0; ni < 4; ni++) {
            int gn = n0 + wc * 64 + ni * 16 + fr;
            float bias = b1[gn];
#pragma unroll
            for (int j = 0; j < 4; j++) {
                int gm = m0 + wr * 32 + mi * 16 + rj + j;
                if (gm < count) {
                    float v = acc[mi][ni][j] + bias;
                    H[(size_t)gm * C_HID + gn] = (bf16_t)(v / (1.0f + __expf(-v)));
                }
            }
        }
    }
}

// ---------------------------------------------------------------------------
// GEMM2 fused: out[rows_dst[m]][n] = scale*(sum_K H[m][k]*W2[n][k] + b2[n])
// 32x128 tile, BK=32, 4 waves (1x4), wave tile 32x32 (2x2 frags), dbuf LDS.
__global__ __launch_bounds__(256) void gemm2_kernel(
    const bf16_t* __restrict__ Hm, const bf16_t* __restrict__ W2b,
    const float* __restrict__ b2, const int* __restrict__ rows_dst,
    const int* __restrict__ countp, const float* __restrict__ scale,
    float* __restrict__ outp) {
    int count = *countp; if (count > PM) count = PM;
    const int m0 = blockIdx.x * 32;
    if (m0 >= count) return;
    const int n0 = blockIdx.y * 128;

    __shared__ __align__(16) bf16_t As[2][32][40];
    __shared__ __align__(16) bf16_t Bs[2][128][40];

    const int t = threadIdx.x;
    const int lane = t & 63;
    const int w = t >> 6;              // wave n-offset = w*32
    const int fr = lane & 15;
    const int kq = (lane >> 4) * 8;

    f32x4 acc[2][2];
#pragma unroll
    for (int i = 0; i < 2; i++)
#pragma unroll
        for (int j = 0; j < 2; j++) acc[i][j] = (f32x4){0.f, 0.f, 0.f, 0.f};

    // A: 32x32 = 128 chunks (threads 0-127); B: 128x32 = 512 chunks (2/thread)
    const int arow = t >> 2, ac8 = (t & 3) * 8;
    const bool astage = (t < 128);
    const bf16_t* ap = Hm + (size_t)(m0 + arow) * C_HID + ac8;   // stale rows harmless
    const int aofs = arow * 40 + ac8;
    const bf16_t* bp[2];
    int bofs[2];
#pragma unroll
    for (int j = 0; j < 2; j++) {
        int c = t + 256 * j;
        int row = c >> 2, c8 = (c & 3) * 8;
        bp[j] = W2b + (size_t)(n0 + row) * C_HID + c8;
        bofs[j] = row * 40 + c8;
    }

    bf16_t* AsF = &As[0][0][0];
    bf16_t* BsF = &Bs[0][0][0];
    const int ABUF = 32 * 40, BBUF = 128 * 40;

    bf16x8 ra;
    if (astage) ra = *(const bf16x8*)(ap);
    bf16x8 rb0 = *(const bf16x8*)(bp[0]);
    bf16x8 rb1 = *(const bf16x8*)(bp[1]);

    const int T = C_HID / 32;   // 24
    for (int tile = 0; tile < T; ++tile) {
        const int cur = tile & 1;
        if (astage) *(bf16x8*)(AsF + cur * ABUF + aofs) = ra;
        *(bf16x8*)(BsF + cur * BBUF + bofs[0]) = rb0;
        *(bf16x8*)(BsF + cur * BBUF + bofs[1]) = rb1;
        bf16x8 na, nb0, nb1;
        bool more = (tile + 1 < T);
        if (more) {
            int k = (tile + 1) * 32;
            if (astage) na = *(const bf16x8*)(ap + k);
            nb0 = *(const bf16x8*)(bp[0] + k);
            nb1 = *(const bf16x8*)(bp[1] + k);
        }
        __syncthreads();
        bf16x8 af[2], bfr[2];
#pragma unroll
        for (int mi = 0; mi < 2; mi++)
            af[mi] = *(const bf16x8*)(AsF + cur * ABUF + (mi * 16 + fr) * 40 + kq);
#pragma unroll
        for (int ni = 0; ni < 2; ni++)
            bfr[ni] = *(const bf16x8*)(BsF + cur * BBUF + (w * 32 + ni * 16 + fr) * 40 + kq);
#pragma unroll
        for (int mi = 0; mi < 2; mi++)
#pragma unroll
            for (int ni = 0; ni < 2; ni++)
                acc[mi][ni] = __builtin_amdgcn_mfma_f32_16x16x32_bf16(
                    af[mi], bfr[ni], acc[mi][ni], 0, 0, 0);
        if (more) { if (astage) ra = na; rb0 = nb0; rb1 = nb1; }
        __syncthreads();
    }

    const float sc = scale[0];
    const int rj = (lane >> 4) * 4;
#pragma unroll
    for (int mi = 0; mi < 2; mi++) {
#pragma unroll
        for (int ni = 0; ni < 2; ni++) {
            int gn = n0 + w * 32 + ni * 16 + fr;
            float bias = b2[gn];
#pragma unroll
            for (int j = 0; j < 2 * 2; j++) ;   // (no-op; keep loop structure simple)
#pragma unroll
            for (int j = 0; j < 4; j++) {
                int gm = m0 + mi * 16 + rj + j;
                if (gm < count) {
                    int dst = rows_dst[gm];
                    outp[(size_t)dst * C_OUT + gn] = sc * (acc[mi][ni][j] + bias);
                }
            }
        }
    }
}

// ---------------------------------------------------------------------------
extern "C" void kernel_launch(void* const* d_in, const int* in_sizes, int n_in,
                              void* d_out, int out_size, void* d_ws, size_t ws_size,
                              hipStream_t stream) {
    const float* X     = (const float*)d_in[0];
    const int*   tm    = (const int*)d_in[1];
    const int*   ctid  = (const int*)d_in[2];
    const int*   cdrid = (const int*)d_in[3];
    const int*   bct   = (const int*)d_in[4];
    const int*   brt   = (const int*)d_in[5];
    const float* W1    = (const float*)d_in[6];
    const float* b1    = (const float*)d_in[7];
    const float* W2    = (const float*)d_in[8];
    const float* b2    = (const float*)d_in[9];
    const float* scale = (const float*)d_in[10];

    char* ws = (char*)d_ws;
    size_t off = 0;
    int* count = (int*)(ws + off);        off += 1024;
    int* vcnt = (int*)(ws + off);         off += 1024;
    int* rows_src = (int*)(ws + off);     off += (size_t)PM * 4;
    int* rows_dst = (int*)(ws + off);     off += (size_t)PM * 4;
    int* trowL = (int*)(ws + off);        off += (size_t)NPAIR * L_TEXT * 4;
    int* pidxL = (int*)(ws + off);        off += (size_t)NPAIR * L_TEXT * 4;
    bf16_t* W1b = (bf16_t*)(ws + off);    off += (size_t)C_HID * C_TEXT * 2;
    bf16_t* W2b = (bf16_t*)(ws + off);    off += (size_t)C_OUT * C_HID * 2;
    bf16_t* Xg = (bf16_t*)(ws + off);     off += (size_t)PM * C_TEXT * 2;
    bf16_t* H = (bf16_t*)(ws + off);      off += (size_t)PM * C_HID * 2;
    float* outp = (float*)d_out;

    init_map_kernel<<<CHUNK_BLOCKS + NPAIR, 256, 0, stream>>>(
        W1, W2, W1b, W2b, outp, tm, ctid, cdrid, bct, brt, trowL, pidxL, vcnt);

    map_write_kernel<<<NPAIR, 64, 0, stream>>>(trowL, pidxL, vcnt,
                                               rows_src, rows_dst, count);

    gather_kernel<<<(PM * GCH) / 256, 256, 0, stream>>>(X, rows_src, count, Xg);

    dim3 g1(PM / 64, C_HID / 128);                 // 48 x 6
    gemm1_kernel<<<g1, 256, 0, stream>>>(Xg, W1b, b1, count, H);

    dim3 g2(PM / 32, C_OUT / 128);                 // 96 x 3
    gemm2_kernel<<<g2, 256, 0, stream>>>(H, W2b, b2, rows_dst, count, scale, outp);
}

// Round 10
// 124.754 us; speedup vs baseline: 3.5276x; 1.1448x over previous
//
#include <hip/hip_runtime.h>
#include <hip/hip_bf16.h>
#include <math.h>

typedef __bf16 bf16_t;
typedef bf16_t bf16x8 __attribute__((ext_vector_type(8)));
typedef bf16_t bf16x4 __attribute__((ext_vector_type(4)));
typedef float f32x4 __attribute__((ext_vector_type(4)));

#define L_TEXT 2048
#define N_TOKEN 2048
#define C_TEXT 3584
#define C_OUT 384
#define C_HID 768
#define BATCH 8
#define MAXROWS (BATCH * N_TOKEN)
#define PM 3072            // capacity for compacted rows (count ~2400)
#define NPAIR (BATCH * 6)
#define KSPLIT 4
#define KCHUNK (C_TEXT / KSPLIT)   // 896

#define NW1 (C_HID * C_TEXT / 8)          // 344064 W1 cvt chunks
#define NW2 (C_OUT * C_HID / 8)           // 36864  W2 cvt chunks
#define NZERO (MAXROWS * C_OUT / 4)       // 1572864 f32x4 zero chunks of d_out
#define CHUNKS_TOTAL (NW1 + NW2 + NZERO)
#define CHUNK_BLOCKS (CHUNKS_TOTAL / 256) // 7632 exactly
#define GCH (C_TEXT / 8)                  // 448 chunks per gathered row

// ---------------------------------------------------------------------------
// init node: W1/W2 fp32->bf16 + zero d_out + 48 per-pair mask-scan blocks
__global__ __launch_bounds__(256) void init_map_kernel(
    const float* __restrict__ W1, const float* __restrict__ W2,
    bf16_t* __restrict__ W1b, bf16_t* __restrict__ W2b,
    float* __restrict__ outp,
    const int* __restrict__ tm, const int* __restrict__ ctid,
    const int* __restrict__ cdrid, const int* __restrict__ bct,
    const int* __restrict__ brt,
    int* __restrict__ trowL, int* __restrict__ pidxL, int* __restrict__ vcnt) {
    if (blockIdx.x >= CHUNK_BLOCKS) {
        const int bp = blockIdx.x - CHUNK_BLOCKS;
        const int lane = threadIdx.x;
        if (lane >= 64) return;
        const int b = bp / 6, p = bp % 6;
        const int ct = (p < 3) ? 1 : 2;
        const int rt = 2 + 2 * (p % 3);
        const unsigned long long ltm = (1ull << lane) - 1ull;

        unsigned int tbits = 0, pbits = 0;
#pragma unroll
        for (int i = 0; i < 32; i++) {
            int l = i * 64 + lane;
            unsigned int m = (ctid[b * L_TEXT + l] == ct) &&
                             (cdrid[b * L_TEXT + l] == rt) &&
                             (tm[b * L_TEXT + l] != 0);
            tbits |= m << i;
        }
#pragma unroll
        for (int i = 0; i < 32; i++) {
            int n = i * 64 + lane;
            unsigned int m = (bct[b * N_TOKEN + n] == ct) &&
                             (brt[b * N_TOKEN + n] == rt);
            pbits |= m << i;
        }
        int base = 0;
#pragma unroll
        for (int i = 0; i < 32; i++) {
            bool m = (tbits >> i) & 1;
            unsigned long long bal = __ballot(m);
            if (m) trowL[bp * L_TEXT + base + __popcll(bal & ltm)] = i * 64 + lane;
            base += __popcll(bal);
        }
        const int n_text = base;
        base = 0;
#pragma unroll
        for (int i = 0; i < 32; i++) {
            bool m = (pbits >> i) & 1;
            unsigned long long bal = __ballot(m);
            if (m) pidxL[bp * L_TEXT + base + __popcll(bal & ltm)] = i * 64 + lane;
            base += __popcll(bal);
        }
        const int n_prot = base;
        if (lane == 0) vcnt[bp] = n_text < n_prot ? n_text : n_prot;
        return;
    }
    int idx = blockIdx.x * 256 + threadIdx.x;
    if (idx < NW1) {
        int i = idx * 8;
        float4 v0 = *(const float4*)(W1 + i);
        float4 v1 = *(const float4*)(W1 + i + 4);
        bf16x8 o;
        o[0] = (bf16_t)v0.x; o[1] = (bf16_t)v0.y; o[2] = (bf16_t)v0.z; o[3] = (bf16_t)v0.w;
        o[4] = (bf16_t)v1.x; o[5] = (bf16_t)v1.y; o[6] = (bf16_t)v1.z; o[7] = (bf16_t)v1.w;
        *(bf16x8*)(W1b + i) = o;
    } else if (idx < NW1 + NW2) {
        int i = (idx - NW1) * 8;
        float4 v0 = *(const float4*)(W2 + i);
        float4 v1 = *(const float4*)(W2 + i + 4);
        bf16x8 o;
        o[0] = (bf16_t)v0.x; o[1] = (bf16_t)v0.y; o[2] = (bf16_t)v0.z; o[3] = (bf16_t)v0.w;
        o[4] = (bf16_t)v1.x; o[5] = (bf16_t)v1.y; o[6] = (bf16_t)v1.z; o[7] = (bf16_t)v1.w;
        *(bf16x8*)(W2b + i) = o;
    } else {
        int z = idx - NW1 - NW2;
        f32x4 zv = (f32x4){0.f, 0.f, 0.f, 0.f};
        *(f32x4*)(outp + (size_t)z * 4) = zv;
    }
}

// ---------------------------------------------------------------------------
// prefix over 48 per-pair counts + deterministic scatter (no atomics)
__global__ __launch_bounds__(64) void map_write_kernel(
    const int* __restrict__ trowL, const int* __restrict__ pidxL,
    const int* __restrict__ vcnt,
    int* __restrict__ rows_src, int* __restrict__ rows_dst,
    int* __restrict__ count) {
    const int bp = blockIdx.x;
    const int b = bp / 6;
    const int lane = threadIdx.x;
    int base = 0, total = 0;
    for (int q = 0; q < NPAIR; q++) {
        int v = vcnt[q];
        if (q < bp) base += v;
        total += v;
    }
    if (bp == 0 && lane == 0) *count = total < PM ? total : PM;
    const int v = vcnt[bp];
    for (int r = lane; r < v; r += 64) {
        int g = base + r;
        if (g < PM) {
            rows_src[g] = b * L_TEXT + trowL[bp * L_TEXT + r];
            rows_dst[g] = b * N_TOKEN + pidxL[bp * L_TEXT + r];
        }
    }
}

// ---------------------------------------------------------------------------
// gather + fp32->bf16 convert of the compacted X rows
__global__ __launch_bounds__(256) void gather_kernel(
    const float* __restrict__ X, const int* __restrict__ rows_src,
    const int* __restrict__ countp, bf16_t* __restrict__ Xg) {
    int count = *countp; if (count > PM) count = PM;
    int idx = blockIdx.x * 256 + threadIdx.x;
    int m = idx / GCH;
    if (m >= count) return;
    int c = (idx % GCH) * 8;
    const float* src = X + (size_t)rows_src[m] * C_TEXT + c;
    float4 v0 = *(const float4*)(src);
    float4 v1 = *(const float4*)(src + 4);
    bf16x8 o;
    o[0] = (bf16_t)v0.x; o[1] = (bf16_t)v0.y; o[2] = (bf16_t)v0.z; o[3] = (bf16_t)v0.w;
    o[4] = (bf16_t)v1.x; o[5] = (bf16_t)v1.y; o[6] = (bf16_t)v1.z; o[7] = (bf16_t)v1.w;
    *(bf16x8*)(Xg + (size_t)m * C_TEXT + c) = o;
}

// ---------------------------------------------------------------------------
// GEMM1 (split-K=4): P[ks][m][n] = sum_{k chunk} Xg[m][k]*W1[n][k]
// 128x128 tile, BK=32, 4 waves (2x2), 4x4 frags, double-buffered LDS. (R5)
__global__ __launch_bounds__(256) void gemm1_kernel(
    const bf16_t* __restrict__ Xg, const bf16_t* __restrict__ W1b,
    const int* __restrict__ countp, float* __restrict__ P) {
    int count = *countp; if (count > PM) count = PM;
    const int m0 = blockIdx.x * 128;
    if (m0 >= count) return;
    const int n0 = blockIdx.y * 128;
    const int kbeg = blockIdx.z * KCHUNK;

    __shared__ __align__(16) bf16_t As[2][128][40];
    __shared__ __align__(16) bf16_t Bs[2][128][40];

    const int t = threadIdx.x;
    const int lane = t & 63;
    const int w = t >> 6;
    const int wr = w >> 1, wc = w & 1;
    const int fr = lane & 15;
    const int kq = (lane >> 4) * 8;

    f32x4 acc[4][4];
#pragma unroll
    for (int i = 0; i < 4; i++)
#pragma unroll
        for (int j = 0; j < 4; j++) acc[i][j] = (f32x4){0.f, 0.f, 0.f, 0.f};

    const bf16_t* ap[2];
    const bf16_t* bp[2];
    int ofs[2];
#pragma unroll
    for (int j = 0; j < 2; j++) {
        int c = t + 256 * j;
        int row = c >> 2, c8 = (c & 3) * 8;
        ap[j] = Xg + (size_t)(m0 + row) * C_TEXT + kbeg + c8;
        bp[j] = W1b + (size_t)(n0 + row) * C_TEXT + kbeg + c8;
        ofs[j] = row * 40 + c8;
    }

    bf16_t* AsF = &As[0][0][0];
    bf16_t* BsF = &Bs[0][0][0];
    const int BUF = 128 * 40;

    bf16x8 ra[2], rb[2];
#pragma unroll
    for (int j = 0; j < 2; j++) { ra[j] = *(const bf16x8*)(ap[j]); rb[j] = *(const bf16x8*)(bp[j]); }

    const int T = KCHUNK / 32;   // 28
    for (int tile = 0; tile < T; ++tile) {
        const int cur = tile & 1;
#pragma unroll
        for (int j = 0; j < 2; j++) {
            *(bf16x8*)(AsF + cur * BUF + ofs[j]) = ra[j];
            *(bf16x8*)(BsF + cur * BUF + ofs[j]) = rb[j];
        }
        bf16x8 na[2], nb[2];
        bool more = (tile + 1 < T);
        if (more) {
            int k = (tile + 1) * 32;
#pragma unroll
            for (int j = 0; j < 2; j++) {
                na[j] = *(const bf16x8*)(ap[j] + k);
                nb[j] = *(const bf16x8*)(bp[j] + k);
            }
        }
        __syncthreads();
        bf16x8 af[4], bfr[4];
#pragma unroll
        for (int mi = 0; mi < 4; mi++)
            af[mi] = *(const bf16x8*)(AsF + cur * BUF + (wr * 64 + mi * 16 + fr) * 40 + kq);
#pragma unroll
        for (int ni = 0; ni < 4; ni++)
            bfr[ni] = *(const bf16x8*)(BsF + cur * BUF + (wc * 64 + ni * 16 + fr) * 40 + kq);
#pragma unroll
        for (int mi = 0; mi < 4; mi++)
#pragma unroll
            for (int ni = 0; ni < 4; ni++)
                acc[mi][ni] = __builtin_amdgcn_mfma_f32_16x16x32_bf16(
                    af[mi], bfr[ni], acc[mi][ni], 0, 0, 0);
        if (more) {
#pragma unroll
            for (int j = 0; j < 2; j++) { ra[j] = na[j]; rb[j] = nb[j]; }
        }
    }

    float* Pk = P + (size_t)blockIdx.z * PM * C_HID;
    const int rj = (lane >> 4) * 4;
#pragma unroll
    for (int mi = 0; mi < 4; mi++) {
#pragma unroll
        for (int ni = 0; ni < 4; ni++) {
            int gn = n0 + wc * 64 + ni * 16 + fr;
#pragma unroll
            for (int j = 0; j < 4; j++) {
                int gm = m0 + wr * 64 + mi * 16 + rj + j;
                if (gm < count) Pk[(size_t)gm * C_HID + gn] = acc[mi][ni][j];
            }
        }
    }
}

// ---------------------------------------------------------------------------
// reduce partials + bias + SiLU -> H (bf16)
__global__ __launch_bounds__(256) void reduce1_kernel(
    const float* __restrict__ P, const float* __restrict__ b1,
    const int* __restrict__ countp, bf16_t* __restrict__ H) {
    int count = *countp; if (count > PM) count = PM;
    int idx = blockIdx.x * 256 + threadIdx.x;
    int m = idx / (C_HID / 4);
    int c = (idx % (C_HID / 4)) * 4;
    if (m >= count) return;
    f32x4 s = *(const f32x4*)(P + (size_t)m * C_HID + c);
#pragma unroll
    for (int ks = 1; ks < KSPLIT; ks++)
        s += *(const f32x4*)(P + ((size_t)ks * PM + m) * C_HID + c);
    f32x4 bb = *(const f32x4*)(b1 + c);
    bf16x4 o;
#pragma unroll
    for (int j = 0; j < 4; j++) {
        float v = s[j] + bb[j];
        o[j] = (bf16_t)(v / (1.0f + __expf(-v)));
    }
    *(bf16x4*)(H + (size_t)m * C_HID + c) = o;
}

// ---------------------------------------------------------------------------
// GEMM2 fused: out[rows_dst[m]][n] = scale*(sum_K H[m][k]*W2[n][k] + b2[n])
// 32x128 tile, BK=32, 4 waves (1x4), wave tile 32x32, dbuf LDS. (R8, proven)
__global__ __launch_bounds__(256) void gemm2_kernel(
    const bf16_t* __restrict__ Hm, const bf16_t* __restrict__ W2b,
    const float* __restrict__ b2, const int* __restrict__ rows_dst,
    const int* __restrict__ countp, const float* __restrict__ scale,
    float* __restrict__ outp) {
    int count = *countp; if (count > PM) count = PM;
    const int m0 = blockIdx.x * 32;
    if (m0 >= count) return;
    const int n0 = blockIdx.y * 128;

    __shared__ __align__(16) bf16_t As[2][32][40];
    __shared__ __align__(16) bf16_t Bs[2][128][40];

    const int t = threadIdx.x;
    const int lane = t & 63;
    const int w = t >> 6;              // wave n-offset = w*32
    const int fr = lane & 15;
    const int kq = (lane >> 4) * 8;

    f32x4 acc[2][2];
#pragma unroll
    for (int i = 0; i < 2; i++)
#pragma unroll
        for (int j = 0; j < 2; j++) acc[i][j] = (f32x4){0.f, 0.f, 0.f, 0.f};

    const int arow = t >> 2, ac8 = (t & 3) * 8;
    const bool astage = (t < 128);
    const bf16_t* ap = Hm + (size_t)(m0 + arow) * C_HID + ac8;   // stale rows harmless
    const int aofs = arow * 40 + ac8;
    const bf16_t* bp[2];
    int bofs[2];
#pragma unroll
    for (int j = 0; j < 2; j++) {
        int c = t + 256 * j;
        int row = c >> 2, c8 = (c & 3) * 8;
        bp[j] = W2b + (size_t)(n0 + row) * C_HID + c8;
        bofs[j] = row * 40 + c8;
    }

    bf16_t* AsF = &As[0][0][0];
    bf16_t* BsF = &Bs[0][0][0];
    const int ABUF = 32 * 40, BBUF = 128 * 40;

    bf16x8 ra;
    if (astage) ra = *(const bf16x8*)(ap);
    bf16x8 rb0 = *(const bf16x8*)(bp[0]);
    bf16x8 rb1 = *(const bf16x8*)(bp[1]);

    const int T = C_HID / 32;   // 24
    for (int tile = 0; tile < T; ++tile) {
        const int cur = tile & 1;
        if (astage) *(bf16x8*)(AsF + cur * ABUF + aofs) = ra;
        *(bf16x8*)(BsF + cur * BBUF + bofs[0]) = rb0;
        *(bf16x8*)(BsF + cur * BBUF + bofs[1]) = rb1;
        bf16x8 na, nb0, nb1;
        bool more = (tile + 1 < T);
        if (more) {
            int k = (tile + 1) * 32;
            if (astage) na = *(const bf16x8*)(ap + k);
            nb0 = *(const bf16x8*)(bp[0] + k);
            nb1 = *(const bf16x8*)(bp[1] + k);
        }
        __syncthreads();
        bf16x8 af[2], bfr[2];
#pragma unroll
        for (int mi = 0; mi < 2; mi++)
            af[mi] = *(const bf16x8*)(AsF + cur * ABUF + (mi * 16 + fr) * 40 + kq);
#pragma unroll
        for (int ni = 0; ni < 2; ni++)
            bfr[ni] = *(const bf16x8*)(BsF + cur * BBUF + (w * 32 + ni * 16 + fr) * 40 + kq);
#pragma unroll
        for (int mi = 0; mi < 2; mi++)
#pragma unroll
            for (int ni = 0; ni < 2; ni++)
                acc[mi][ni] = __builtin_amdgcn_mfma_f32_16x16x32_bf16(
                    af[mi], bfr[ni], acc[mi][ni], 0, 0, 0);
        if (more) { if (astage) ra = na; rb0 = nb0; rb1 = nb1; }
        __syncthreads();
    }

    const float sc = scale[0];
    const int rj = (lane >> 4) * 4;
#pragma unroll
    for (int mi = 0; mi < 2; mi++) {
#pragma unroll
        for (int ni = 0; ni < 2; ni++) {
            int gn = n0 + w * 32 + ni * 16 + fr;
            float bias = b2[gn];
#pragma unroll
            for (int j = 0; j < 4; j++) {
                int gm = m0 + mi * 16 + rj + j;
                if (gm < count) {
                    int dst = rows_dst[gm];
                    outp[(size_t)dst * C_OUT + gn] = sc * (acc[mi][ni][j] + bias);
                }
            }
        }
    }
}

// ---------------------------------------------------------------------------
extern "C" void kernel_launch(void* const* d_in, const int* in_sizes, int n_in,
                              void* d_out, int out_size, void* d_ws, size_t ws_size,
                              hipStream_t stream) {
    const float* X     = (const float*)d_in[0];
    const int*   tm    = (const int*)d_in[1];
    const int*   ctid  = (const int*)d_in[2];
    const int*   cdrid = (const int*)d_in[3];
    const int*   bct   = (const int*)d_in[4];
    const int*   brt   = (const int*)d_in[5];
    const float* W1    = (const float*)d_in[6];
    const float* b1    = (const float*)d_in[7];
    const float* W2    = (const float*)d_in[8];
    const float* b2    = (const float*)d_in[9];
    const float* scale = (const float*)d_in[10];

    char* ws = (char*)d_ws;
    size_t off = 0;
    int* count = (int*)(ws + off);        off += 1024;
    int* vcnt = (int*)(ws + off);         off += 1024;
    int* rows_src = (int*)(ws + off);     off += (size_t)PM * 4;
    int* rows_dst = (int*)(ws + off);     off += (size_t)PM * 4;
    int* trowL = (int*)(ws + off);        off += (size_t)NPAIR * L_TEXT * 4;
    int* pidxL = (int*)(ws + off);        off += (size_t)NPAIR * L_TEXT * 4;
    bf16_t* W1b = (bf16_t*)(ws + off);    off += (size_t)C_HID * C_TEXT * 2;
    bf16_t* W2b = (bf16_t*)(ws + off);    off += (size_t)C_OUT * C_HID * 2;
    bf16_t* Xg = (bf16_t*)(ws + off);     off += (size_t)PM * C_TEXT * 2;
    bf16_t* H = (bf16_t*)(ws + off);      off += (size_t)PM * C_HID * 2;
    float* P = (float*)(ws + off);        off += (size_t)KSPLIT * PM * C_HID * 4;
    float* outp = (float*)d_out;

    init_map_kernel<<<CHUNK_BLOCKS + NPAIR, 256, 0, stream>>>(
        W1, W2, W1b, W2b, outp, tm, ctid, cdrid, bct, brt, trowL, pidxL, vcnt);

    map_write_kernel<<<NPAIR, 64, 0, stream>>>(trowL, pidxL, vcnt,
                                               rows_src, rows_dst, count);

    gather_kernel<<<(PM * GCH) / 256, 256, 0, stream>>>(X, rows_src, count, Xg);

    dim3 g1(PM / 128, C_HID / 128, KSPLIT);         // 24 x 6 x 4
    gemm1_kernel<<<g1, 256, 0, stream>>>(Xg, W1b, count, P);

    reduce1_kernel<<<(PM * C_HID / 4) / 256, 256, 0, stream>>>(P, b1, count, H);

    dim3 g2(PM / 32, C_OUT / 128);                  // 96 x 3
    gemm2_kernel<<<g2, 256, 0, stream>>>(H, W2b, b2, rows_dst, count, scale, outp);
}